// Round 8
// baseline (608.049 us; speedup 1.0000x reference)
//
#include <hip/hip_runtime.h>
#include <cstdint>

using u8 = unsigned char;
using u64 = unsigned long long;

typedef _Float16 f16x8 __attribute__((ext_vector_type(8)));
typedef float f32x4 __attribute__((ext_vector_type(4)));
typedef int i32x4 __attribute__((ext_vector_type(4)));
typedef signed char i8x8 __attribute__((ext_vector_type(8)));
typedef unsigned short u16x8 __attribute__((ext_vector_type(8)));

__device__ __forceinline__ void gload16(const void* g, void* l) {
  __builtin_amdgcn_global_load_lds((const __attribute__((address_space(1))) void*)g,
                                   (__attribute__((address_space(3))) void*)l, 16, 0, 0);
}

#define VMCNT(N) asm volatile("s_waitcnt vmcnt(" #N ")" ::: "memory")

// quant scale: clip |x|<=5, q = rint(x*127/5)
#define QSCALE 25.4f
#define DEQ2 (0.03937007874f * 0.03937007874f)

// ---- convert fp32 [B][C][N] -> f16 hi/lo planes + i8 plane, all [B][N][C] --
// lo = exact residual scaled x4096. Optionally per-c-chunk partial sum-sq.
template <bool WITH_HN>
__global__ __launch_bounds__(256) void split_convert(const float* __restrict__ in,
                                                     _Float16* __restrict__ hi,
                                                     _Float16* __restrict__ lo,
                                                     signed char* __restrict__ q8,
                                                     float* __restrict__ hnp,
                                                     int C, int N) {
  const int n = blockIdx.y * 256 + threadIdx.x;
  const int c0 = blockIdx.x * 32;
  const int b = blockIdx.z;
  const float* inB = in + (size_t)b * C * N;
  f16x8 hv[4], lv[4];
  i8x8 qv[4];
  float ss = 0.f;
#pragma unroll
  for (int g = 0; g < 4; ++g)
#pragma unroll
    for (int e = 0; e < 8; ++e) {
      float x = inB[(size_t)(c0 + g * 8 + e) * N + n];
      _Float16 h = (_Float16)x;
      float r = (x - (float)h) * 4096.f;
      hv[g][e] = h;
      lv[g][e] = (_Float16)r;
      int qi = (int)rintf(x * QSCALE);
      qi = qi > 127 ? 127 : (qi < -127 ? -127 : qi);
      qv[g][e] = (signed char)qi;
      if (WITH_HN) ss = fmaf(x, x, ss);
    }
  _Float16* oh = hi + ((size_t)b * N + n) * C + c0;
  _Float16* ol = lo + ((size_t)b * N + n) * C + c0;
  signed char* oq = q8 + ((size_t)b * N + n) * C + c0;
#pragma unroll
  for (int g = 0; g < 4; ++g) {
    *(f16x8*)(oh + g * 8) = hv[g];
    *(f16x8*)(ol + g * 8) = lv[g];
    *(i8x8*)(oq + g * 8) = qv[g];
  }
  if (WITH_HN)
    hnp[((size_t)b * gridDim.x + blockIdx.x) * N + n] = ss;
}

// ---- hn[b][n] = 0.5 * sum over chunks of hnp --------------------------------
__global__ __launch_bounds__(256) void hn_reduce(const float* __restrict__ hnp,
                                                 float* __restrict__ hn,
                                                 int NC, int N) {
  const int n = blockIdx.x * 256 + threadIdx.x;
  const int b = blockIdx.y;
  float acc = 0.f;
  for (int cc = 0; cc < NC; ++cc) acc += hnp[((size_t)b * NC + cc) * N + n];
  hn[(size_t)b * N + n] = 0.5f * acc;
}

// ---- i8 filter GEMM, round-6-validated phase schedule -----------------------
// K-tile per X = 128 i8 (two 64-k half-chunks); fragments 16 B/lane, identical
// byte layout for A and B (k-permutation-consistent => exact i32 dot).
#define MFMA_BLOCK(GI)                                                         \
  __builtin_amdgcn_s_barrier();                                                \
  asm volatile("s_waitcnt lgkmcnt(0)" ::: "memory");                           \
  __builtin_amdgcn_sched_barrier(0);                                           \
  __builtin_amdgcn_s_setprio(1);                                               \
  _Pragma("unroll") for (int i2 = 0; i2 < 4; ++i2)                             \
      _Pragma("unroll") for (int j = 0; j < NJ; ++j) acc[(GI)*4 + i2][j] =     \
      __builtin_amdgcn_mfma_i32_16x16x64_i8(av[i2], bv[j],                     \
                                            acc[(GI)*4 + i2][j], 0, 0, 0);     \
  __builtin_amdgcn_s_setprio(0);                                               \
  asm volatile("" ::: "memory");                                               \
  __builtin_amdgcn_s_barrier();

template <int MI, int NJ, int WCN, int NTH>
__global__ __launch_bounds__(NTH, 2) void nn_filter_i8(
    const signed char* __restrict__ Aq, const signed char* __restrict__ Bq,
    const float* __restrict__ hn, unsigned short* __restrict__ sc,
    int M, int N, int NT /* K/128 */, int mBlocks, int nBlocks) {
  constexpr int BM = 2 * MI * 16;
  constexpr int G = MI / 4;
  constexpr int CHUNK_A = BM * 64;
  constexpr int CHUNK = 2 * CHUNK_A;
  __shared__ u8 smem[4 * CHUNK];

  const int tid = threadIdx.x;
  const int lane = tid & 63;
  const int wid = tid >> 6;
  const int wrow = wid / WCN;
  const int wcol = wid % WCN;
  const int lr = lane & 15, kh = lane >> 4;

  const int cpx = (int)gridDim.x >> 3;
  const int bid = (int)blockIdx.x;
  const int sbid = (bid & 7) * cpx + (bid >> 3);
  const int perB = mBlocks * nBlocks;
  const int b = sbid / perB;
  const int rr = sbid - b * perB;
  const int n1 = rr & 3;
  const int t2 = rr >> 2;
  const int mb = t2 % mBlocks;
  const int n2 = t2 / mBlocks;
  const int mbase = mb * BM;
  const int nbase = (n2 * 4 + n1) * BM;
  const size_t rstride = (size_t)NT * 128;  // = K bytes

  const int r0 = (tid >> 6) * 16 + ((tid & 63) >> 2);
  const int sA = ((lane & 3) ^ (r0 >> 1)) & 3;
  const u8* aP0 = (const u8*)Aq + ((size_t)b * M + mbase + r0) * rstride + sA * 16;
  const u8* aP1 = aP0 + (size_t)(NTH / 4) * rstride;
  const u8* bP0 = (const u8*)Bq + ((size_t)b * N + nbase + r0) * rstride + sA * 16;
  const u8* bP1 = bP0 + (size_t)(NTH / 4) * rstride;

  auto STAGE = [&](int X, int h) {
    const size_t ko = (size_t)X * 128 + h * 64;
    u8* cb = smem + ((X & 1) * 2 + h) * CHUNK;
    gload16(aP0 + ko, cb + tid * 16);
    gload16(aP1 + ko, cb + NTH * 16 + tid * 16);
    gload16(bP0 + ko, cb + CHUNK_A + tid * 16);
    gload16(bP1 + ko, cb + CHUNK_A + NTH * 16 + tid * 16);
  };

  int a_off[MI], b_off[NJ];
#pragma unroll
  for (int i = 0; i < MI; ++i) {
    const int row = wrow * (MI * 16) + i * 16 + lr;
    a_off[i] = row * 64 + (((kh ^ (row >> 1)) & 3) << 4);
  }
#pragma unroll
  for (int j = 0; j < NJ; ++j) {
    const int row = wcol * (NJ * 16) + j * 16 + lr;
    b_off[j] = CHUNK_A + row * 64 + (((kh ^ (row >> 1)) & 3) << 4);
  }

  i32x4 acc[MI][NJ];
#pragma unroll
  for (int i = 0; i < MI; ++i)
#pragma unroll
    for (int j = 0; j < NJ; ++j) acc[i][j] = i32x4{0, 0, 0, 0};

  STAGE(0, 0);
  STAGE(0, 1);
  STAGE(1, 0);
  VMCNT(8);
  __builtin_amdgcn_s_barrier();

  for (int X = 0; X < NT; ++X) {
    const u8* cb0 = smem + ((X & 1) * 2) * CHUNK;
    const u8* cb1 = cb0 + CHUNK;
    i32x4 av[4], bv[NJ];

#pragma unroll
    for (int j = 0; j < NJ; ++j) bv[j] = *(const i32x4*)(cb0 + b_off[j]);
#pragma unroll
    for (int i2 = 0; i2 < 4; ++i2) av[i2] = *(const i32x4*)(cb0 + a_off[i2]);
    if (X + 1 < NT) STAGE(X + 1, 1);
    if (X + 1 < NT) { VMCNT(8); } else { VMCNT(0); }
    MFMA_BLOCK(0)

    if constexpr (G == 2) {
#pragma unroll
      for (int i2 = 0; i2 < 4; ++i2) av[i2] = *(const i32x4*)(cb0 + a_off[4 + i2]);
      MFMA_BLOCK(1)
    }

#pragma unroll
    for (int j = 0; j < NJ; ++j) bv[j] = *(const i32x4*)(cb1 + b_off[j]);
#pragma unroll
    for (int i2 = 0; i2 < 4; ++i2) av[i2] = *(const i32x4*)(cb1 + a_off[i2]);
    if (X + 2 < NT) STAGE(X + 2, 0);
    if (X + 1 < NT) {
      if (X + 2 < NT) { VMCNT(8); } else { VMCNT(4); }
    }
    MFMA_BLOCK(0)

    if constexpr (G == 2) {
#pragma unroll
      for (int i2 = 0; i2 < 4; ++i2) av[i2] = *(const i32x4*)(cb1 + a_off[4 + i2]);
      MFMA_BLOCK(1)
    }
  }

  // epilogue: dequant + quantized score store. C/D: col=lane&15, row=(lane>>4)*4+r
  const float* hnB = hn + (size_t)b * N;
  float hnv[NJ];
  int ncol[NJ];
#pragma unroll
  for (int j = 0; j < NJ; ++j) {
    ncol[j] = nbase + wcol * (NJ * 16) + j * 16 + lr;
    hnv[j] = hnB[ncol[j]];
  }
  unsigned short* scB = sc + (size_t)b * M * N;
#pragma unroll
  for (int i = 0; i < MI; ++i)
#pragma unroll
    for (int r = 0; r < 4; ++r) {
      const int m = mbase + wrow * (MI * 16) + i * 16 + kh * 4 + r;
      unsigned short* srow = scB + (size_t)m * N;
#pragma unroll
      for (int j = 0; j < NJ; ++j) {
        float score = hnv[j] - (float)acc[i][j][r] * DEQ2;
        int qi = (int)(score * 64.0f);
        qi = qi < 0 ? 0 : (qi > 65535 ? 65535 : qi);
        srow[ncol[j]] = (unsigned short)qi;
      }
    }
}

// ---- select + exact rescore: one wave per source row ------------------------
template <int K, int CH>
__global__ __launch_bounds__(256) void select_rescore(
    const unsigned short* __restrict__ sc,
    const _Float16* __restrict__ hiA, const _Float16* __restrict__ loA,
    const _Float16* __restrict__ hiB, const _Float16* __restrict__ loB,
    const float* __restrict__ hn, unsigned* __restrict__ idx,
    int M, int N, int dq /* threshold in u16 units */) {
  const int w = threadIdx.x >> 6, lane = threadIdx.x & 63;
  const int row = blockIdx.x * 4 + w;
  const int b = blockIdx.y;
  const unsigned short* q = sc + ((size_t)b * M + row) * N;

  unsigned cm[CH];
#pragma unroll
  for (int ch = 0; ch < CH; ++ch) {
    u16x8 v = *(const u16x8*)(q + ch * 512 + lane * 8);
    unsigned m0 = v[0] < v[1] ? v[0] : v[1];
    unsigned m1 = v[2] < v[3] ? v[2] : v[3];
    unsigned m2 = v[4] < v[5] ? v[4] : v[5];
    unsigned m3 = v[6] < v[7] ? v[6] : v[7];
    m0 = m0 < m1 ? m0 : m1;
    m2 = m2 < m3 ? m2 : m3;
    unsigned m = m0 < m2 ? m0 : m2;
#pragma unroll
    for (int off = 32; off >= 1; off >>= 1) {
      unsigned o = (unsigned)__shfl_xor((int)m, off);
      m = o < m ? o : m;
    }
    cm[ch] = m;
  }
  unsigned mn = 0xFFFFu;
#pragma unroll
  for (int ch = 0; ch < CH; ++ch) mn = cm[ch] < mn ? cm[ch] : mn;
  const unsigned thr = mn + dq;

  constexpr int PER = K / 64;
  const float inv = 2.44140625e-4f;
  float sv[PER];
  const _Float16* hA = hiA + ((size_t)b * M + row) * K;
  const _Float16* lA = loA + ((size_t)b * M + row) * K;
#pragma unroll
  for (int i = 0; i < PER; ++i)
    sv[i] = fmaf((float)lA[i * 64 + lane], inv, (float)hA[i * 64 + lane]);

  float bestv = 3.4e38f;
  int bestn = 0x7FFFFFFF;
  const float* hnB = hn + (size_t)b * N;
#pragma unroll
  for (int ch = 0; ch < CH; ++ch) {
    if (cm[ch] > thr) continue;
    u16x8 v = *(const u16x8*)(q + ch * 512 + lane * 8);
#pragma unroll
    for (int e = 0; e < 8; ++e) {
      u64 mask = __ballot((unsigned)v[e] <= thr);
      while (mask) {
        int bit = __ffsll((long long)mask) - 1;
        mask &= mask - 1;
        int n = ch * 512 + bit * 8 + e;
        const _Float16* hB = hiB + ((size_t)b * N + n) * K;
        const _Float16* lB = loB + ((size_t)b * N + n) * K;
        float part = 0.f;
#pragma unroll
        for (int i = 0; i < PER; ++i)
          part = fmaf(sv[i], fmaf((float)lB[i * 64 + lane], inv, (float)hB[i * 64 + lane]), part);
#pragma unroll
        for (int off = 32; off >= 1; off >>= 1) part += __shfl_xor(part, off);
        float scf = hnB[n] - part;
        if (scf < bestv || (scf == bestv && n < bestn)) { bestv = scf; bestn = n; }
      }
    }
  }
  if (lane == 0) idx[(size_t)b * M + row] = (unsigned)bestn;
}

// ---- write c1 = [src1 | gather(tar1, idx1)] ---------------------------------
__global__ __launch_bounds__(256) void write_c1(const float* __restrict__ src1,
                                                const float* __restrict__ tar1,
                                                const unsigned* __restrict__ idx,
                                                float* __restrict__ out) {
  const int b = blockIdx.y, c = blockIdx.x;  // c in [0,2048)
  float* orow = out + ((size_t)b * 6144 + c) * 4096;
  if (c < 1024) {
    const float4* s4 = (const float4*)(src1 + ((size_t)b * 1024 + c) * 4096);
    float4* o4 = (float4*)orow;
#pragma unroll
    for (int i = 0; i < 4; ++i) o4[threadIdx.x + i * 256] = s4[threadIdx.x + i * 256];
  } else {
    const float* trow = tar1 + ((size_t)b * 1024 + (c - 1024)) * 4096;
    const unsigned* ib = idx + (size_t)b * 4096;
    for (int p = threadIdx.x; p < 4096; p += 256) orow[p] = trow[ib[p]];
  }
}

// ---- bilinear x2 upsample of c2 = [src2 | gather(tar2, idx2)] ---------------
__global__ __launch_bounds__(256) void upsample2(const float* __restrict__ src2,
                                                 const float* __restrict__ tar2,
                                                 const unsigned* __restrict__ idx2,
                                                 float* __restrict__ out) {
  __shared__ float row[1024];
  int b = blockIdx.y, c = blockIdx.x;
  if (c < 2048) {
    const float* in = src2 + ((size_t)b * 2048 + c) * 1024;
    for (int p = threadIdx.x; p < 1024; p += 256) row[p] = in[p];
  } else {
    const float* trow = tar2 + ((size_t)b * 2048 + (c - 2048)) * 1024;
    const unsigned* ib = idx2 + (size_t)b * 1024;
    for (int p = threadIdx.x; p < 1024; p += 256) row[p] = trow[ib[p]];
  }
  __syncthreads();
  float* orow = out + ((size_t)b * 6144 + 2048 + c) * 4096;
  for (int q = threadIdx.x; q < 4096; q += 256) {
    int y = q >> 6, x = q & 63;
    int ky = y >> 1, kx = x >> 1;
    int y0, y1, x0, x1;
    float wy0, wy1, wx0, wx1;
    if (y & 1) { y0 = ky; y1 = (ky + 1 < 32) ? ky + 1 : 31; wy0 = 0.75f; wy1 = 0.25f; }
    else       { y0 = (ky > 0) ? ky - 1 : 0; y1 = ky;       wy0 = 0.25f; wy1 = 0.75f; }
    if (x & 1) { x0 = kx; x1 = (kx + 1 < 32) ? kx + 1 : 31; wx0 = 0.75f; wx1 = 0.25f; }
    else       { x0 = (kx > 0) ? kx - 1 : 0; x1 = kx;       wx0 = 0.25f; wx1 = 0.75f; }
    float v = wy0 * (wx0 * row[y0 * 32 + x0] + wx1 * row[y0 * 32 + x1]) +
              wy1 * (wx0 * row[y1 * 32 + x0] + wx1 * row[y1 * 32 + x1]);
    orow[q] = v;
  }
}

// ---------------- launch -----------------------------------------------------
extern "C" void kernel_launch(void* const* d_in, const int* in_sizes, int n_in,
                              void* d_out, int out_size, void* d_ws, size_t ws_size,
                              hipStream_t stream) {
  const float* src1 = (const float*)d_in[0];  // [4,1024,64,64]
  const float* tar1 = (const float*)d_in[1];
  const float* src2 = (const float*)d_in[2];  // [4,2048,32,32]
  const float* tar2 = (const float*)d_in[3];
  float* out = (float*)d_out;                 // [4,6144,64,64] = 384 MiB

  // scratch in d_out (consumed before the final output writes):
  u8* scratch = (u8*)d_out;
  _Float16* hi1s = (_Float16*)scratch;                       // 32 MiB [4,4096,1024]
  _Float16* lo1s = (_Float16*)(scratch + (32ull << 20));     // 32 MiB
  _Float16* hi1t = (_Float16*)(scratch + (64ull << 20));     // 32 MiB
  _Float16* lo1t = (_Float16*)(scratch + (96ull << 20));     // 32 MiB
  _Float16* hi2s = (_Float16*)(scratch + (128ull << 20));    // 16 MiB [4,1024,2048]
  _Float16* lo2s = (_Float16*)(scratch + (144ull << 20));    // 16 MiB
  _Float16* hi2t = (_Float16*)(scratch + (160ull << 20));    // 16 MiB
  _Float16* lo2t = (_Float16*)(scratch + (176ull << 20));    // 16 MiB
  unsigned short* sc1 = (unsigned short*)(scratch + (192ull << 20));  // 128 MiB
  unsigned short* sc2 = (unsigned short*)(scratch + (320ull << 20));  // 8 MiB
  float* hnp1 = (float*)(scratch + (328ull << 20));          // 2 MiB [4,32,4096]
  float* hnp2 = (float*)(scratch + (331ull << 20));          // 1 MiB [4,64,1024]
  signed char* q1s = (signed char*)(scratch + (332ull << 20));  // 16 MiB
  signed char* q1t = (signed char*)(scratch + (348ull << 20));  // 16 MiB
  signed char* q2s = (signed char*)(scratch + (364ull << 20));  // 8 MiB
  signed char* q2t = (signed char*)(scratch + (372ull << 20));  // 8 MiB -> 380

  float* hn1 = (float*)d_ws;              // 4*4096 f32
  float* hn2 = hn1 + 4 * 4096;            // 4*1024 f32
  unsigned* idx1 = (unsigned*)(hn2 + 4 * 1024);  // 4*4096 u32
  unsigned* idx2 = idx1 + 4 * 4096;              // 4*1024 u32

  split_convert<false><<<dim3(32, 16, 4), 256, 0, stream>>>(src1, hi1s, lo1s, q1s, nullptr, 1024, 4096);
  split_convert<true><<<dim3(32, 16, 4), 256, 0, stream>>>(tar1, hi1t, lo1t, q1t, hnp1, 1024, 4096);
  split_convert<false><<<dim3(64, 4, 4), 256, 0, stream>>>(src2, hi2s, lo2s, q2s, nullptr, 2048, 1024);
  split_convert<true><<<dim3(64, 4, 4), 256, 0, stream>>>(tar2, hi2t, lo2t, q2t, hnp2, 2048, 1024);

  hn_reduce<<<dim3(16, 4), 256, 0, stream>>>(hnp1, hn1, 32, 4096);
  hn_reduce<<<dim3(4, 4), 256, 0, stream>>>(hnp2, hn2, 64, 1024);

  // level 1: 256x256 tile, M=N=4096, K=1024 (NT=8); 16x16 blocks x4 = 1024
  nn_filter_i8<8, 4, 4, 512><<<1024, 512, 0, stream>>>(
      q1s, q1t, hn1, sc1, 4096, 4096, 8, 16, 16);
  // level 2: 128x128 tile, M=N=1024, K=2048 (NT=16); 8x8 blocks x4 = 256
  nn_filter_i8<4, 4, 2, 256><<<256, 256, 0, stream>>>(
      q2s, q2t, hn2, sc2, 1024, 1024, 16, 8, 8);

  // Delta = 5.0 (L1) / 6.0 (L2) in score units -> *64 in u16 units
  select_rescore<1024, 8><<<dim3(1024, 4), 256, 0, stream>>>(
      sc1, hi1s, lo1s, hi1t, lo1t, hn1, idx1, 4096, 4096, 320);
  select_rescore<2048, 2><<<dim3(256, 4), 256, 0, stream>>>(
      sc2, hi2s, lo2s, hi2t, lo2t, hn2, idx2, 1024, 1024, 384);

  write_c1<<<dim3(2048, 4), 256, 0, stream>>>(src1, tar1, idx1, out);
  upsample2<<<dim3(4096, 4), 256, 0, stream>>>(src2, tar2, idx2, out);
}

// Round 9
// 591.785 us; speedup vs baseline: 1.0275x; 1.0275x over previous
//
#include <hip/hip_runtime.h>
#include <cstdint>

using u8 = unsigned char;
using u64 = unsigned long long;

typedef _Float16 f16x8 __attribute__((ext_vector_type(8)));
typedef float f32x4 __attribute__((ext_vector_type(4)));
typedef unsigned short u16x8 __attribute__((ext_vector_type(8)));

__device__ __forceinline__ void gload16(const void* g, void* l) {
  __builtin_amdgcn_global_load_lds((const __attribute__((address_space(1))) void*)g,
                                   (__attribute__((address_space(3))) void*)l, 16, 0, 0);
}

#define VMCNT(N) asm volatile("s_waitcnt vmcnt(" #N ")" ::: "memory")

// ---- convert fp32 [B][C][N] -> dense fp16 planes hi[B][N][C], lo[B][N][C] ---
// lo = exact residual scaled x4096. Optionally per-c-chunk partial sum-sq.
template <bool WITH_HN>
__global__ __launch_bounds__(256) void split_convert(const float* __restrict__ in,
                                                     _Float16* __restrict__ hi,
                                                     _Float16* __restrict__ lo,
                                                     float* __restrict__ hnp,
                                                     int C, int N) {
  const int n = blockIdx.y * 256 + threadIdx.x;
  const int c0 = blockIdx.x * 32;
  const int b = blockIdx.z;
  const float* inB = in + (size_t)b * C * N;
  f16x8 hv[4], lv[4];
  float ss = 0.f;
#pragma unroll
  for (int g = 0; g < 4; ++g)
#pragma unroll
    for (int e = 0; e < 8; ++e) {
      float x = inB[(size_t)(c0 + g * 8 + e) * N + n];
      _Float16 h = (_Float16)x;
      float r = (x - (float)h) * 4096.f;
      hv[g][e] = h;
      lv[g][e] = (_Float16)r;
      if (WITH_HN) ss = fmaf(x, x, ss);
    }
  _Float16* oh = hi + ((size_t)b * N + n) * C + c0;
  _Float16* ol = lo + ((size_t)b * N + n) * C + c0;
#pragma unroll
  for (int g = 0; g < 4; ++g) {
    *(f16x8*)(oh + g * 8) = hv[g];
    *(f16x8*)(ol + g * 8) = lv[g];
  }
  if (WITH_HN)
    hnp[((size_t)b * gridDim.x + blockIdx.x) * N + n] = ss;
}

// ---- hn[b][n] = 0.5 * sum over chunks of hnp --------------------------------
__global__ __launch_bounds__(256) void hn_reduce(const float* __restrict__ hnp,
                                                 float* __restrict__ hn,
                                                 int NC, int N) {
  const int n = blockIdx.x * 256 + threadIdx.x;
  const int b = blockIdx.y;
  float acc = 0.f;
  for (int cc = 0; cc < NC; ++cc) acc += hnp[((size_t)b * NC + cc) * N + n];
  hn[(size_t)b * N + n] = 0.5f * acc;
}

// ---- f16-hi filter GEMM (round-7-validated body) + candidate-list epilogue --
#define MFMA_BLOCK(GI)                                                         \
  __builtin_amdgcn_s_barrier();                                                \
  asm volatile("s_waitcnt lgkmcnt(0)" ::: "memory");                           \
  __builtin_amdgcn_sched_barrier(0);                                           \
  __builtin_amdgcn_s_setprio(1);                                               \
  _Pragma("unroll") for (int i2 = 0; i2 < 4; ++i2)                             \
      _Pragma("unroll") for (int j = 0; j < NJ; ++j) acc[(GI)*4 + i2][j] =     \
      __builtin_amdgcn_mfma_f32_16x16x32_f16(av[i2], bv[j],                    \
                                             acc[(GI)*4 + i2][j], 0, 0, 0);    \
  __builtin_amdgcn_s_setprio(0);                                               \
  asm volatile("" ::: "memory");                                               \
  __builtin_amdgcn_s_barrier();

constexpr int CAP = 12;       // max entries per (row, n-tile)
constexpr unsigned DELTA_Q = 64;  // 1.0 in score units (x64 quant)

template <int MI, int NJ, int WCN, int NTH>
__global__ __launch_bounds__(NTH, 2) void nn_filter8(
    const u8* __restrict__ Ahi, const u8* __restrict__ Bhi,
    const float* __restrict__ hn,
    unsigned* __restrict__ g_cnt, unsigned* __restrict__ g_ent,
    int M, int N, int NT /* K/64 */, int mBlocks, int nBlocks) {
  constexpr int BM = 2 * MI * 16;
  constexpr int G = MI / 4;
  constexpr int CHUNK_A = BM * 64;
  constexpr int CHUNK = 2 * CHUNK_A;
  __shared__ u8 smem[4 * CHUNK];

  const int tid = threadIdx.x;
  const int lane = tid & 63;
  const int wid = tid >> 6;
  const int wrow = wid / WCN;
  const int wcol = wid % WCN;
  const int lr = lane & 15, kh = lane >> 4;

  const int cpx = (int)gridDim.x >> 3;
  const int bid = (int)blockIdx.x;
  const int sbid = (bid & 7) * cpx + (bid >> 3);
  const int perB = mBlocks * nBlocks;
  const int b = sbid / perB;
  const int rr = sbid - b * perB;
  const int n1 = rr & 3;
  const int t2 = rr >> 2;
  const int mb = t2 % mBlocks;
  const int n2 = t2 / mBlocks;
  const int mbase = mb * BM;
  const int tileIdx = n2 * 4 + n1;
  const int nbase = tileIdx * BM;
  const size_t rstride = (size_t)NT * 128;

  const int r0 = (tid >> 6) * 16 + ((tid & 63) >> 2);
  const int sA = ((lane & 3) ^ (r0 >> 1)) & 3;
  const u8* aP0 = Ahi + ((size_t)b * M + mbase + r0) * rstride + sA * 16;
  const u8* aP1 = aP0 + (size_t)(NTH / 4) * rstride;
  const u8* bP0 = Bhi + ((size_t)b * N + nbase + r0) * rstride + sA * 16;
  const u8* bP1 = bP0 + (size_t)(NTH / 4) * rstride;

  auto STAGE = [&](int X, int h) {
    const size_t ko = (size_t)X * 128 + h * 64;
    u8* cb = smem + ((X & 1) * 2 + h) * CHUNK;
    gload16(aP0 + ko, cb + tid * 16);
    gload16(aP1 + ko, cb + NTH * 16 + tid * 16);
    gload16(bP0 + ko, cb + CHUNK_A + tid * 16);
    gload16(bP1 + ko, cb + CHUNK_A + NTH * 16 + tid * 16);
  };

  int a_off[MI], b_off[NJ];
#pragma unroll
  for (int i = 0; i < MI; ++i) {
    const int row = wrow * (MI * 16) + i * 16 + lr;
    a_off[i] = row * 64 + (((kh ^ (row >> 1)) & 3) << 4);
  }
#pragma unroll
  for (int j = 0; j < NJ; ++j) {
    const int row = wcol * (NJ * 16) + j * 16 + lr;
    b_off[j] = CHUNK_A + row * 64 + (((kh ^ (row >> 1)) & 3) << 4);
  }

  f32x4 acc[MI][NJ];
#pragma unroll
  for (int i = 0; i < MI; ++i)
#pragma unroll
    for (int j = 0; j < NJ; ++j) acc[i][j] = f32x4{0.f, 0.f, 0.f, 0.f};

  STAGE(0, 0);
  STAGE(0, 1);
  STAGE(1, 0);
  VMCNT(8);
  __builtin_amdgcn_s_barrier();

  for (int X = 0; X < NT; ++X) {
    const u8* cb0 = smem + ((X & 1) * 2) * CHUNK;
    const u8* cb1 = cb0 + CHUNK;
    f16x8 av[4], bv[NJ];

#pragma unroll
    for (int j = 0; j < NJ; ++j) bv[j] = *(const f16x8*)(cb0 + b_off[j]);
#pragma unroll
    for (int i2 = 0; i2 < 4; ++i2) av[i2] = *(const f16x8*)(cb0 + a_off[i2]);
    if (X + 1 < NT) STAGE(X + 1, 1);
    if (X + 1 < NT) { VMCNT(8); } else { VMCNT(0); }
    MFMA_BLOCK(0)

    if constexpr (G == 2) {
#pragma unroll
      for (int i2 = 0; i2 < 4; ++i2) av[i2] = *(const f16x8*)(cb0 + a_off[4 + i2]);
      MFMA_BLOCK(1)
    }

#pragma unroll
    for (int j = 0; j < NJ; ++j) bv[j] = *(const f16x8*)(cb1 + b_off[j]);
#pragma unroll
    for (int i2 = 0; i2 < 4; ++i2) av[i2] = *(const f16x8*)(cb1 + a_off[i2]);
    if (X + 2 < NT) STAGE(X + 2, 0);
    if (X + 1 < NT) {
      if (X + 2 < NT) { VMCNT(8); } else { VMCNT(4); }
    }
    MFMA_BLOCK(0)

    if constexpr (G == 2) {
#pragma unroll
      for (int i2 = 0; i2 < 4; ++i2) av[i2] = *(const f16x8*)(cb1 + a_off[4 + i2]);
      MFMA_BLOCK(1)
    }
  }

  // ---- epilogue: per-(row, tile) candidate lists ----------------------------
  // q = clamp((hn - dot)*64). Pass1: row tile-min (shfl over 16 lr-lanes +
  // LDS across WCN wave-cols). Pass2: push q <= tilemin+DELTA into LDS list.
  // Flush one writer per row; no global atomics.
  const float* hnB = hn + (size_t)b * N;
  float hnv[NJ];
  int ncol[NJ];
#pragma unroll
  for (int j = 0; j < NJ; ++j) {
    ncol[j] = nbase + wcol * (NJ * 16) + j * 16 + lr;
    hnv[j] = hnB[ncol[j]];
  }

  unsigned* lmin = (unsigned*)smem;                       // [BM][WCN]
  unsigned* tmin = (unsigned*)(smem + BM * WCN * 4);      // [BM]
  unsigned* lcnt = tmin + BM;                             // [BM]
  unsigned* lent = lcnt + BM;                             // [BM][CAP]

  auto quant = [&](int i, int j, int r) -> unsigned {
    float s = hnv[j] - acc[i][j][r];
    int qi = (int)(s * 64.0f);
    return (unsigned)(qi < 0 ? 0 : (qi > 65535 ? 65535 : qi));
  };

  // pass 1: wave-level row mins
#pragma unroll
  for (int i = 0; i < MI; ++i)
#pragma unroll
    for (int r = 0; r < 4; ++r) {
      unsigned rq = 0xFFFFFFFFu;
#pragma unroll
      for (int j = 0; j < NJ; ++j) {
        unsigned q = quant(i, j, r);
        rq = q < rq ? q : rq;
      }
#pragma unroll
      for (int off = 1; off <= 8; off <<= 1) {
        unsigned o = (unsigned)__shfl_xor((int)rq, off);
        rq = o < rq ? o : rq;
      }
      if (lr == 0) {
        const int ml = wrow * (MI * 16) + i * 16 + kh * 4 + r;
        lmin[ml * WCN + wcol] = rq;
      }
    }
  __syncthreads();
  for (int m = tid; m < BM; m += NTH) {
    unsigned t = lmin[m * WCN];
#pragma unroll
    for (int w = 1; w < WCN; ++w) {
      unsigned o = lmin[m * WCN + w];
      t = o < t ? o : t;
    }
    tmin[m] = t;
    lcnt[m] = 0;
  }
  __syncthreads();
  // pass 2: push
#pragma unroll
  for (int i = 0; i < MI; ++i)
#pragma unroll
    for (int r = 0; r < 4; ++r) {
      const int ml = wrow * (MI * 16) + i * 16 + kh * 4 + r;
      const unsigned lim = tmin[ml] + DELTA_Q;
#pragma unroll
      for (int j = 0; j < NJ; ++j) {
        unsigned q = quant(i, j, r);
        if (q <= lim) {
          unsigned slot = atomicAdd(&lcnt[ml], 1u);
          if (slot < CAP) lent[ml * CAP + slot] = (q << 16) | (unsigned)ncol[j];
        }
      }
    }
  __syncthreads();
  // flush
  for (int m = tid; m < BM; m += NTH) {
    unsigned c = lcnt[m];
    unsigned cc = c < CAP ? c : CAP;
    const size_t base = ((size_t)b * M + mbase + m) * nBlocks + tileIdx;
    g_cnt[base] = cc;
    for (unsigned e = 0; e < cc; ++e) g_ent[base * CAP + e] = lent[m * CAP + e];
  }
}

// ---- select from candidate lists + exact fp32 rescore (one wave per row) ----
template <int K, int NTILES>
__global__ __launch_bounds__(256) void select_cand(
    const unsigned* __restrict__ g_cnt, const unsigned* __restrict__ g_ent,
    const _Float16* __restrict__ hiA, const _Float16* __restrict__ loA,
    const _Float16* __restrict__ hiB, const _Float16* __restrict__ loB,
    const float* __restrict__ hn, unsigned* __restrict__ idx, int M, int N) {
  const int w = threadIdx.x >> 6, lane = threadIdx.x & 63;
  const int row = blockIdx.x * 4 + w;
  const int b = blockIdx.y;
  const size_t rowbase = ((size_t)b * M + row) * NTILES;

  // min packed key (q<<16|n) over all entries; lane t handles tile t
  unsigned key = 0xFFFFFFFFu;
  if (lane < NTILES) {
    unsigned c = g_cnt[rowbase + lane];
    for (unsigned e = 0; e < c; ++e) {
      unsigned en = g_ent[(rowbase + lane) * CAP + e];
      key = en < key ? en : key;
    }
  }
#pragma unroll
  for (int off = 32; off >= 1; off >>= 1) {
    unsigned o = (unsigned)__shfl_xor((int)key, off);
    key = o < key ? o : key;
  }
  const unsigned thr = (key >> 16) + DELTA_Q;

  constexpr int PER = K / 64;
  const float inv = 2.44140625e-4f;
  float sv[PER];
  const _Float16* hA = hiA + ((size_t)b * M + row) * K;
  const _Float16* lA = loA + ((size_t)b * M + row) * K;
#pragma unroll
  for (int i = 0; i < PER; ++i)
    sv[i] = fmaf((float)lA[i * 64 + lane], inv, (float)hA[i * 64 + lane]);

  float bestv = 3.4e38f;
  int bestn = 0x7FFFFFFF;
  const float* hnB = hn + (size_t)b * N;
  for (int t = 0; t < NTILES; ++t) {
    unsigned c = g_cnt[rowbase + t];  // uniform -> broadcast
    for (unsigned e = 0; e < c; ++e) {
      unsigned en = g_ent[(rowbase + t) * CAP + e];
      if ((en >> 16) > thr) continue;
      int n = (int)(en & 0xFFFFu);
      const _Float16* hB = hiB + ((size_t)b * N + n) * K;
      const _Float16* lB = loB + ((size_t)b * N + n) * K;
      float part = 0.f;
#pragma unroll
      for (int i = 0; i < PER; ++i)
        part = fmaf(sv[i], fmaf((float)lB[i * 64 + lane], inv, (float)hB[i * 64 + lane]), part);
#pragma unroll
      for (int off = 32; off >= 1; off >>= 1) part += __shfl_xor(part, off);
      float scf = hnB[n] - part;
      if (scf < bestv || (scf == bestv && n < bestn)) { bestv = scf; bestn = n; }
    }
  }
  if (lane == 0) idx[(size_t)b * M + row] = (unsigned)bestn;
}

// ---- write c1 = [src1 | gather(tar1, idx1)] ---------------------------------
__global__ __launch_bounds__(256) void write_c1(const float* __restrict__ src1,
                                                const float* __restrict__ tar1,
                                                const unsigned* __restrict__ idx,
                                                float* __restrict__ out) {
  const int b = blockIdx.y, c = blockIdx.x;  // c in [0,2048)
  float* orow = out + ((size_t)b * 6144 + c) * 4096;
  if (c < 1024) {
    const float4* s4 = (const float4*)(src1 + ((size_t)b * 1024 + c) * 4096);
    float4* o4 = (float4*)orow;
#pragma unroll
    for (int i = 0; i < 4; ++i) o4[threadIdx.x + i * 256] = s4[threadIdx.x + i * 256];
  } else {
    const float* trow = tar1 + ((size_t)b * 1024 + (c - 1024)) * 4096;
    const unsigned* ib = idx + (size_t)b * 4096;
    for (int p = threadIdx.x; p < 4096; p += 256) orow[p] = trow[ib[p]];
  }
}

// ---- bilinear x2 upsample of c2 = [src2 | gather(tar2, idx2)] ---------------
__global__ __launch_bounds__(256) void upsample2(const float* __restrict__ src2,
                                                 const float* __restrict__ tar2,
                                                 const unsigned* __restrict__ idx2,
                                                 float* __restrict__ out) {
  __shared__ float row[1024];
  int b = blockIdx.y, c = blockIdx.x;
  if (c < 2048) {
    const float* in = src2 + ((size_t)b * 2048 + c) * 1024;
    for (int p = threadIdx.x; p < 1024; p += 256) row[p] = in[p];
  } else {
    const float* trow = tar2 + ((size_t)b * 2048 + (c - 2048)) * 1024;
    const unsigned* ib = idx2 + (size_t)b * 1024;
    for (int p = threadIdx.x; p < 1024; p += 256) row[p] = trow[ib[p]];
  }
  __syncthreads();
  float* orow = out + ((size_t)b * 6144 + 2048 + c) * 4096;
  for (int q = threadIdx.x; q < 4096; q += 256) {
    int y = q >> 6, x = q & 63;
    int ky = y >> 1, kx = x >> 1;
    int y0, y1, x0, x1;
    float wy0, wy1, wx0, wx1;
    if (y & 1) { y0 = ky; y1 = (ky + 1 < 32) ? ky + 1 : 31; wy0 = 0.75f; wy1 = 0.25f; }
    else       { y0 = (ky > 0) ? ky - 1 : 0; y1 = ky;       wy0 = 0.25f; wy1 = 0.75f; }
    if (x & 1) { x0 = kx; x1 = (kx + 1 < 32) ? kx + 1 : 31; wx0 = 0.75f; wx1 = 0.25f; }
    else       { x0 = (kx > 0) ? kx - 1 : 0; x1 = kx;       wx0 = 0.25f; wx1 = 0.75f; }
    float v = wy0 * (wx0 * row[y0 * 32 + x0] + wx1 * row[y0 * 32 + x1]) +
              wy1 * (wx0 * row[y1 * 32 + x0] + wx1 * row[y1 * 32 + x1]);
    orow[q] = v;
  }
}

// ---------------- launch -----------------------------------------------------
extern "C" void kernel_launch(void* const* d_in, const int* in_sizes, int n_in,
                              void* d_out, int out_size, void* d_ws, size_t ws_size,
                              hipStream_t stream) {
  const float* src1 = (const float*)d_in[0];  // [4,1024,64,64]
  const float* tar1 = (const float*)d_in[1];
  const float* src2 = (const float*)d_in[2];  // [4,2048,32,32]
  const float* tar2 = (const float*)d_in[3];
  float* out = (float*)d_out;                 // [4,6144,64,64] = 384 MiB

  // scratch in d_out (consumed before the final output writes):
  u8* scratch = (u8*)d_out;
  _Float16* hi1s = (_Float16*)scratch;                       // 32 MiB [4,4096,1024]
  _Float16* lo1s = (_Float16*)(scratch + (32ull << 20));     // 32 MiB
  _Float16* hi1t = (_Float16*)(scratch + (64ull << 20));     // 32 MiB
  _Float16* lo1t = (_Float16*)(scratch + (96ull << 20));     // 32 MiB
  _Float16* hi2s = (_Float16*)(scratch + (128ull << 20));    // 16 MiB [4,1024,2048]
  _Float16* lo2s = (_Float16*)(scratch + (144ull << 20));    // 16 MiB
  _Float16* hi2t = (_Float16*)(scratch + (160ull << 20));    // 16 MiB
  _Float16* lo2t = (_Float16*)(scratch + (176ull << 20));    // 16 MiB
  float* hnp1 = (float*)(scratch + (192ull << 20));          // 2 MiB [4,32,4096]
  float* hnp2 = (float*)(scratch + (195ull << 20));          // 1 MiB [4,64,1024]
  unsigned* cnt1 = (unsigned*)(scratch + (200ull << 20));    // 1 MiB [4][4096][16]
  unsigned* ent1 = (unsigned*)(scratch + (202ull << 20));    // 12 MiB [...][CAP]
  unsigned* cnt2 = (unsigned*)(scratch + (216ull << 20));    // 128 KiB [4][1024][8]
  unsigned* ent2 = (unsigned*)(scratch + (218ull << 20));    // 1.5 MiB

  float* hn1 = (float*)d_ws;              // 4*4096 f32
  float* hn2 = hn1 + 4 * 4096;            // 4*1024 f32
  unsigned* idx1 = (unsigned*)(hn2 + 4 * 1024);  // 4*4096 u32
  unsigned* idx2 = idx1 + 4 * 4096;              // 4*1024 u32

  split_convert<false><<<dim3(32, 16, 4), 256, 0, stream>>>(src1, hi1s, lo1s, nullptr, 1024, 4096);
  split_convert<true><<<dim3(32, 16, 4), 256, 0, stream>>>(tar1, hi1t, lo1t, hnp1, 1024, 4096);
  split_convert<false><<<dim3(64, 4, 4), 256, 0, stream>>>(src2, hi2s, lo2s, nullptr, 2048, 1024);
  split_convert<true><<<dim3(64, 4, 4), 256, 0, stream>>>(tar2, hi2t, lo2t, hnp2, 2048, 1024);

  hn_reduce<<<dim3(16, 4), 256, 0, stream>>>(hnp1, hn1, 32, 4096);
  hn_reduce<<<dim3(4, 4), 256, 0, stream>>>(hnp2, hn2, 64, 1024);

  // level 1: 256x256 tile, M=N=4096, K=1024 (NT=16); 16x16 blocks x4 = 1024
  nn_filter8<8, 4, 4, 512><<<1024, 512, 0, stream>>>(
      (const u8*)hi1s, (const u8*)hi1t, hn1, cnt1, ent1, 4096, 4096, 16, 16, 16);
  // level 2: 128x128 tile, M=N=1024, K=2048 (NT=32); 8x8 blocks x4 = 256
  nn_filter8<4, 4, 2, 256><<<256, 256, 0, stream>>>(
      (const u8*)hi2s, (const u8*)hi2t, hn2, cnt2, ent2, 1024, 1024, 32, 8, 8);

  select_cand<1024, 16><<<dim3(1024, 4), 256, 0, stream>>>(
      cnt1, ent1, hi1s, lo1s, hi1t, lo1t, hn1, idx1, 4096, 4096);
  select_cand<2048, 8><<<dim3(256, 4), 256, 0, stream>>>(
      cnt2, ent2, hi2s, lo2s, hi2t, lo2t, hn2, idx2, 1024, 1024);

  write_c1<<<dim3(2048, 4), 256, 0, stream>>>(src1, tar1, idx1, out);
  upsample2<<<dim3(4096, 4), 256, 0, stream>>>(src2, tar2, idx2, out);
}

// Round 10
// 558.894 us; speedup vs baseline: 1.0879x; 1.0588x over previous
//
#include <hip/hip_runtime.h>
#include <cstdint>

using u8 = unsigned char;
using u64 = unsigned long long;

typedef _Float16 f16x8 __attribute__((ext_vector_type(8)));
typedef float f32x4 __attribute__((ext_vector_type(4)));
typedef unsigned short u16x8 __attribute__((ext_vector_type(8)));

__device__ __forceinline__ void gload16(const void* g, void* l) {
  __builtin_amdgcn_global_load_lds((const __attribute__((address_space(1))) void*)g,
                                   (__attribute__((address_space(3))) void*)l, 16, 0, 0);
}

#define VMCNT(N) asm volatile("s_waitcnt vmcnt(" #N ")" ::: "memory")

// ---- fp32 [C][N] slice -> f16 hi/lo planes [N][C] (+ optional partial sum-sq)
__device__ __forceinline__ void split_body(const float* __restrict__ in,
                                           _Float16* __restrict__ hi,
                                           _Float16* __restrict__ lo,
                                           float* __restrict__ hnp,
                                           int C, int N, int NC,
                                           int cblk, int nblk, int b, bool with_hn) {
  const int n = nblk * 256 + (int)threadIdx.x;
  const int c0 = cblk * 32;
  const float* inB = in + (size_t)b * C * N;
  f16x8 hv[4], lv[4];
  float ss = 0.f;
#pragma unroll
  for (int g = 0; g < 4; ++g)
#pragma unroll
    for (int e = 0; e < 8; ++e) {
      float x = inB[(size_t)(c0 + g * 8 + e) * N + n];
      _Float16 h = (_Float16)x;
      float r = (x - (float)h) * 4096.f;
      hv[g][e] = h;
      lv[g][e] = (_Float16)r;
      ss = fmaf(x, x, ss);
    }
  _Float16* oh = hi + ((size_t)b * N + n) * C + c0;
  _Float16* ol = lo + ((size_t)b * N + n) * C + c0;
#pragma unroll
  for (int g = 0; g < 4; ++g) {
    *(f16x8*)(oh + g * 8) = hv[g];
    *(f16x8*)(ol + g * 8) = lv[g];
  }
  if (with_hn) hnp[((size_t)b * NC + cblk) * N + n] = ss;
}

// one launch for all 4 tensors: flat grid 2048*2 (L1) + 1024*2 (L2) = 6144
__global__ __launch_bounds__(256) void prep_all(
    const float* __restrict__ s1, const float* __restrict__ t1,
    const float* __restrict__ s2, const float* __restrict__ t2,
    _Float16* __restrict__ h1s, _Float16* __restrict__ l1s,
    _Float16* __restrict__ h1t, _Float16* __restrict__ l1t,
    _Float16* __restrict__ h2s, _Float16* __restrict__ l2s,
    _Float16* __restrict__ h2t, _Float16* __restrict__ l2t,
    float* __restrict__ hnp1, float* __restrict__ hnp2) {
  const int f = (int)blockIdx.x;
  if (f < 4096) {  // L1: C=1024, N=4096; 32 c-blocks x 16 n-blocks x 4 b
    const bool isT = f >= 2048;
    const int local = f & 2047;
    const int cblk = local & 31;
    const int r = local >> 5;
    const int nblk = r & 15, b = r >> 4;
    split_body(isT ? t1 : s1, isT ? h1t : h1s, isT ? l1t : l1s, hnp1,
               1024, 4096, 32, cblk, nblk, b, isT);
  } else {         // L2: C=2048, N=1024; 64 c-blocks x 4 n-blocks x 4 b
    const int l0 = f - 4096;
    const bool isT = l0 >= 1024;
    const int local = l0 & 1023;
    const int cblk = local & 63;
    const int r = local >> 6;
    const int nblk = r & 3, b = r >> 2;
    split_body(isT ? t2 : s2, isT ? h2t : h2s, isT ? l2t : l2s, hnp2,
               2048, 1024, 64, cblk, nblk, b, isT);
  }
}

// ---- hn[b][n] = 0.5 * sum over chunks, both levels in one launch ------------
__global__ __launch_bounds__(256) void hn_all(const float* __restrict__ hnp1,
                                              const float* __restrict__ hnp2,
                                              float* __restrict__ hn1,
                                              float* __restrict__ hn2) {
  const int x = (int)blockIdx.x, b = (int)blockIdx.y;
  if (x < 16) {
    const int n = x * 256 + (int)threadIdx.x;
    float a = 0.f;
    for (int cc = 0; cc < 32; ++cc) a += hnp1[((size_t)b * 32 + cc) * 4096 + n];
    hn1[(size_t)b * 4096 + n] = 0.5f * a;
  } else {
    const int n = (x - 16) * 256 + (int)threadIdx.x;
    float a = 0.f;
    for (int cc = 0; cc < 64; ++cc) a += hnp2[((size_t)b * 64 + cc) * 1024 + n];
    hn2[(size_t)b * 1024 + n] = 0.5f * a;
  }
}

// ---- f16-hi filter GEMM, round-6/7-validated phase schedule -----------------
#define MFMA_BLOCK(GI)                                                         \
  __builtin_amdgcn_s_barrier();                                                \
  asm volatile("s_waitcnt lgkmcnt(0)" ::: "memory");                           \
  __builtin_amdgcn_sched_barrier(0);                                           \
  __builtin_amdgcn_s_setprio(1);                                               \
  _Pragma("unroll") for (int i2 = 0; i2 < 4; ++i2)                             \
      _Pragma("unroll") for (int j = 0; j < NJ; ++j) acc[(GI)*4 + i2][j] =     \
      __builtin_amdgcn_mfma_f32_16x16x32_f16(av[i2], bv[j],                    \
                                             acc[(GI)*4 + i2][j], 0, 0, 0);    \
  __builtin_amdgcn_s_setprio(0);                                               \
  asm volatile("" ::: "memory");                                               \
  __builtin_amdgcn_s_barrier();

template <int MI, int NJ, int WCN, int NTH>
__global__ __launch_bounds__(NTH, 2) void nn_filter8(
    const u8* __restrict__ Ahi, const u8* __restrict__ Bhi,
    const float* __restrict__ hn, unsigned short* __restrict__ sc,
    int M, int N, int NT /* K/64 */, int mBlocks, int nBlocks) {
  constexpr int BM = 2 * MI * 16;
  constexpr int G = MI / 4;
  constexpr int CHUNK_A = BM * 64;
  constexpr int CHUNK = 2 * CHUNK_A;
  __shared__ u8 smem[4 * CHUNK];

  const int tid = threadIdx.x;
  const int lane = tid & 63;
  const int wid = tid >> 6;
  const int wrow = wid / WCN;
  const int wcol = wid % WCN;
  const int lr = lane & 15, kh = lane >> 4;

  const int cpx = (int)gridDim.x >> 3;
  const int bid = (int)blockIdx.x;
  const int sbid = (bid & 7) * cpx + (bid >> 3);
  const int perB = mBlocks * nBlocks;
  const int b = sbid / perB;
  const int rr = sbid - b * perB;
  const int n1 = rr & 3;
  const int t2 = rr >> 2;
  const int mb = t2 % mBlocks;
  const int n2 = t2 / mBlocks;
  const int mbase = mb * BM;
  const int nbase = (n2 * 4 + n1) * BM;
  const size_t rstride = (size_t)NT * 128;

  const int r0 = (tid >> 6) * 16 + ((tid & 63) >> 2);
  const int sA = ((lane & 3) ^ (r0 >> 1)) & 3;
  const u8* aP0 = Ahi + ((size_t)b * M + mbase + r0) * rstride + sA * 16;
  const u8* aP1 = aP0 + (size_t)(NTH / 4) * rstride;
  const u8* bP0 = Bhi + ((size_t)b * N + nbase + r0) * rstride + sA * 16;
  const u8* bP1 = bP0 + (size_t)(NTH / 4) * rstride;

  auto STAGE = [&](int X, int h) {
    const size_t ko = (size_t)X * 128 + h * 64;
    u8* cb = smem + ((X & 1) * 2 + h) * CHUNK;
    gload16(aP0 + ko, cb + tid * 16);
    gload16(aP1 + ko, cb + NTH * 16 + tid * 16);
    gload16(bP0 + ko, cb + CHUNK_A + tid * 16);
    gload16(bP1 + ko, cb + CHUNK_A + NTH * 16 + tid * 16);
  };

  int a_off[MI], b_off[NJ];
#pragma unroll
  for (int i = 0; i < MI; ++i) {
    const int row = wrow * (MI * 16) + i * 16 + lr;
    a_off[i] = row * 64 + (((kh ^ (row >> 1)) & 3) << 4);
  }
#pragma unroll
  for (int j = 0; j < NJ; ++j) {
    const int row = wcol * (NJ * 16) + j * 16 + lr;
    b_off[j] = CHUNK_A + row * 64 + (((kh ^ (row >> 1)) & 3) << 4);
  }

  f32x4 acc[MI][NJ];
#pragma unroll
  for (int i = 0; i < MI; ++i)
#pragma unroll
    for (int j = 0; j < NJ; ++j) acc[i][j] = f32x4{0.f, 0.f, 0.f, 0.f};

  STAGE(0, 0);
  STAGE(0, 1);
  STAGE(1, 0);
  VMCNT(8);
  __builtin_amdgcn_s_barrier();

  for (int X = 0; X < NT; ++X) {
    const u8* cb0 = smem + ((X & 1) * 2) * CHUNK;
    const u8* cb1 = cb0 + CHUNK;
    f16x8 av[4], bv[NJ];

#pragma unroll
    for (int j = 0; j < NJ; ++j) bv[j] = *(const f16x8*)(cb0 + b_off[j]);
#pragma unroll
    for (int i2 = 0; i2 < 4; ++i2) av[i2] = *(const f16x8*)(cb0 + a_off[i2]);
    if (X + 1 < NT) STAGE(X + 1, 1);
    if (X + 1 < NT) { VMCNT(8); } else { VMCNT(0); }
    MFMA_BLOCK(0)

    if constexpr (G == 2) {
#pragma unroll
      for (int i2 = 0; i2 < 4; ++i2) av[i2] = *(const f16x8*)(cb0 + a_off[4 + i2]);
      MFMA_BLOCK(1)
    }

#pragma unroll
    for (int j = 0; j < NJ; ++j) bv[j] = *(const f16x8*)(cb1 + b_off[j]);
#pragma unroll
    for (int i2 = 0; i2 < 4; ++i2) av[i2] = *(const f16x8*)(cb1 + a_off[i2]);
    if (X + 2 < NT) STAGE(X + 2, 0);
    if (X + 1 < NT) {
      if (X + 2 < NT) { VMCNT(8); } else { VMCNT(4); }
    }
    MFMA_BLOCK(0)

    if constexpr (G == 2) {
#pragma unroll
      for (int i2 = 0; i2 < 4; ++i2) av[i2] = *(const f16x8*)(cb1 + a_off[4 + i2]);
      MFMA_BLOCK(1)
    }
  }

  // epilogue: quantized score store. C/D: col=lane&15, row=(lane>>4)*4+r
  const float* hnB = hn + (size_t)b * N;
  float hnv[NJ];
  int ncol[NJ];
#pragma unroll
  for (int j = 0; j < NJ; ++j) {
    ncol[j] = nbase + wcol * (NJ * 16) + j * 16 + lr;
    hnv[j] = hnB[ncol[j]];
  }
  unsigned short* scB = sc + (size_t)b * M * N;
#pragma unroll
  for (int i = 0; i < MI; ++i)
#pragma unroll
    for (int r = 0; r < 4; ++r) {
      const int m = mbase + wrow * (MI * 16) + i * 16 + kh * 4 + r;
      unsigned short* srow = scB + (size_t)m * N;
#pragma unroll
      for (int j = 0; j < NJ; ++j) {
        float score = hnv[j] - acc[i][j][r];
        int qi = (int)(score * 64.0f);
        qi = qi < 0 ? 0 : (qi > 65535 ? 65535 : qi);
        srow[ncol[j]] = (unsigned short)qi;
      }
    }
}

// ---- select + exact rescore: one wave per source row (round-7 body) ---------
template <int K, int CH>
__global__ __launch_bounds__(256) void select_rescore(
    const unsigned short* __restrict__ sc,
    const _Float16* __restrict__ hiA, const _Float16* __restrict__ loA,
    const _Float16* __restrict__ hiB, const _Float16* __restrict__ loB,
    const float* __restrict__ hn, unsigned* __restrict__ idx, int M, int N) {
  const int w = threadIdx.x >> 6, lane = threadIdx.x & 63;
  const int row = blockIdx.x * 4 + w;
  const int b = blockIdx.y;
  const unsigned short* q = sc + ((size_t)b * M + row) * N;

  unsigned cm[CH];
#pragma unroll
  for (int ch = 0; ch < CH; ++ch) {
    u16x8 v = *(const u16x8*)(q + ch * 512 + lane * 8);
    unsigned m0 = v[0] < v[1] ? v[0] : v[1];
    unsigned m1 = v[2] < v[3] ? v[2] : v[3];
    unsigned m2 = v[4] < v[5] ? v[4] : v[5];
    unsigned m3 = v[6] < v[7] ? v[6] : v[7];
    m0 = m0 < m1 ? m0 : m1;
    m2 = m2 < m3 ? m2 : m3;
    unsigned m = m0 < m2 ? m0 : m2;
#pragma unroll
    for (int off = 32; off >= 1; off >>= 1) {
      unsigned o = (unsigned)__shfl_xor((int)m, off);
      m = o < m ? o : m;
    }
    cm[ch] = m;
  }
  unsigned mn = 0xFFFFu;
#pragma unroll
  for (int ch = 0; ch < CH; ++ch) mn = cm[ch] < mn ? cm[ch] : mn;
  const unsigned thr = mn + 64;

  constexpr int PER = K / 64;
  const float inv = 2.44140625e-4f;
  float sv[PER];
  const _Float16* hA = hiA + ((size_t)b * M + row) * K;
  const _Float16* lA = loA + ((size_t)b * M + row) * K;
#pragma unroll
  for (int i = 0; i < PER; ++i)
    sv[i] = fmaf((float)lA[i * 64 + lane], inv, (float)hA[i * 64 + lane]);

  float bestv = 3.4e38f;
  int bestn = 0x7FFFFFFF;
  const float* hnB = hn + (size_t)b * N;
#pragma unroll
  for (int ch = 0; ch < CH; ++ch) {
    if (cm[ch] > thr) continue;
    u16x8 v = *(const u16x8*)(q + ch * 512 + lane * 8);
#pragma unroll
    for (int e = 0; e < 8; ++e) {
      u64 mask = __ballot((unsigned)v[e] <= thr);
      while (mask) {
        int bit = __ffsll((long long)mask) - 1;
        mask &= mask - 1;
        int n = ch * 512 + bit * 8 + e;
        const _Float16* hB = hiB + ((size_t)b * N + n) * K;
        const _Float16* lB = loB + ((size_t)b * N + n) * K;
        float part = 0.f;
#pragma unroll
        for (int i = 0; i < PER; ++i)
          part = fmaf(sv[i], fmaf((float)lB[i * 64 + lane], inv, (float)hB[i * 64 + lane]), part);
#pragma unroll
        for (int off = 32; off >= 1; off >>= 1) part += __shfl_xor(part, off);
        float scf = hnB[n] - part;
        if (scf < bestv || (scf == bestv && n < bestn)) { bestv = scf; bestn = n; }
      }
    }
  }
  if (lane == 0) idx[(size_t)b * M + row] = (unsigned)bestn;
}

// ---- finalize: c1 = [src1|gather] and upsampled c2, one launch --------------
__global__ __launch_bounds__(256) void finalize(
    const float* __restrict__ src1, const float* __restrict__ tar1,
    const float* __restrict__ src2, const float* __restrict__ tar2,
    const unsigned* __restrict__ idx1, const unsigned* __restrict__ idx2,
    float* __restrict__ out) {
  const int b = blockIdx.y;
  int c = (int)blockIdx.x;
  if (c < 2048) {
    float* orow = out + ((size_t)b * 6144 + c) * 4096;
    if (c < 1024) {
      const float4* s4 = (const float4*)(src1 + ((size_t)b * 1024 + c) * 4096);
      float4* o4 = (float4*)orow;
#pragma unroll
      for (int i = 0; i < 4; ++i) o4[threadIdx.x + i * 256] = s4[threadIdx.x + i * 256];
    } else {
      const float* trow = tar1 + ((size_t)b * 1024 + (c - 1024)) * 4096;
      const unsigned* ib = idx1 + (size_t)b * 4096;
      for (int p = threadIdx.x; p < 4096; p += 256) orow[p] = trow[ib[p]];
    }
    return;
  }
  c -= 2048;  // upsample channel 0..4095
  __shared__ float row[1024];
  if (c < 2048) {
    const float* in = src2 + ((size_t)b * 2048 + c) * 1024;
    for (int p = threadIdx.x; p < 1024; p += 256) row[p] = in[p];
  } else {
    const float* trow = tar2 + ((size_t)b * 2048 + (c - 2048)) * 1024;
    const unsigned* ib = idx2 + (size_t)b * 1024;
    for (int p = threadIdx.x; p < 1024; p += 256) row[p] = trow[ib[p]];
  }
  __syncthreads();
  float* orow = out + ((size_t)b * 6144 + 2048 + c) * 4096;
  for (int q = threadIdx.x; q < 4096; q += 256) {
    int y = q >> 6, x = q & 63;
    int ky = y >> 1, kx = x >> 1;
    int y0, y1, x0, x1;
    float wy0, wy1, wx0, wx1;
    if (y & 1) { y0 = ky; y1 = (ky + 1 < 32) ? ky + 1 : 31; wy0 = 0.75f; wy1 = 0.25f; }
    else       { y0 = (ky > 0) ? ky - 1 : 0; y1 = ky;       wy0 = 0.25f; wy1 = 0.75f; }
    if (x & 1) { x0 = kx; x1 = (kx + 1 < 32) ? kx + 1 : 31; wx0 = 0.75f; wx1 = 0.25f; }
    else       { x0 = (kx > 0) ? kx - 1 : 0; x1 = kx;       wx0 = 0.25f; wx1 = 0.75f; }
    float v = wy0 * (wx0 * row[y0 * 32 + x0] + wx1 * row[y0 * 32 + x1]) +
              wy1 * (wx0 * row[y1 * 32 + x0] + wx1 * row[y1 * 32 + x1]);
    orow[q] = v;
  }
}

// ---------------- launch -----------------------------------------------------
extern "C" void kernel_launch(void* const* d_in, const int* in_sizes, int n_in,
                              void* d_out, int out_size, void* d_ws, size_t ws_size,
                              hipStream_t stream) {
  const float* src1 = (const float*)d_in[0];  // [4,1024,64,64]
  const float* tar1 = (const float*)d_in[1];
  const float* src2 = (const float*)d_in[2];  // [4,2048,32,32]
  const float* tar2 = (const float*)d_in[3];
  float* out = (float*)d_out;                 // [4,6144,64,64] = 384 MiB

  // scratch in d_out (consumed before the final output writes):
  u8* scratch = (u8*)d_out;
  _Float16* hi1s = (_Float16*)scratch;                       // 32 MiB [4,4096,1024]
  _Float16* lo1s = (_Float16*)(scratch + (32ull << 20));     // 32 MiB
  _Float16* hi1t = (_Float16*)(scratch + (64ull << 20));     // 32 MiB
  _Float16* lo1t = (_Float16*)(scratch + (96ull << 20));     // 32 MiB
  _Float16* hi2s = (_Float16*)(scratch + (128ull << 20));    // 16 MiB [4,1024,2048]
  _Float16* lo2s = (_Float16*)(scratch + (144ull << 20));    // 16 MiB
  _Float16* hi2t = (_Float16*)(scratch + (160ull << 20));    // 16 MiB
  _Float16* lo2t = (_Float16*)(scratch + (176ull << 20));    // 16 MiB
  unsigned short* sc1 = (unsigned short*)(scratch + (192ull << 20));  // 128 MiB
  unsigned short* sc2 = (unsigned short*)(scratch + (320ull << 20));  // 8 MiB
  float* hnp1 = (float*)(scratch + (328ull << 20));          // 2 MiB [4,32,4096]
  float* hnp2 = (float*)(scratch + (331ull << 20));          // 1 MiB [4,64,1024]

  float* hn1 = (float*)d_ws;              // 4*4096 f32
  float* hn2 = hn1 + 4 * 4096;            // 4*1024 f32
  unsigned* idx1 = (unsigned*)(hn2 + 4 * 1024);  // 4*4096 u32
  unsigned* idx2 = idx1 + 4 * 4096;              // 4*1024 u32

  prep_all<<<6144, 256, 0, stream>>>(src1, tar1, src2, tar2,
                                     hi1s, lo1s, hi1t, lo1t,
                                     hi2s, lo2s, hi2t, lo2t, hnp1, hnp2);
  hn_all<<<dim3(20, 4), 256, 0, stream>>>(hnp1, hnp2, hn1, hn2);

  // level 1: 256x256 tile, M=N=4096, K=1024 (NT=16); 16x16 blocks x4 = 1024
  nn_filter8<8, 4, 4, 512><<<1024, 512, 0, stream>>>(
      (const u8*)hi1s, (const u8*)hi1t, hn1, sc1, 4096, 4096, 16, 16, 16);
  // level 2: 128x128 tile, M=N=1024, K=2048 (NT=32); 8x8 blocks x4 = 256
  nn_filter8<4, 4, 2, 256><<<256, 256, 0, stream>>>(
      (const u8*)hi2s, (const u8*)hi2t, hn2, sc2, 1024, 1024, 32, 8, 8);

  select_rescore<1024, 8><<<dim3(1024, 4), 256, 0, stream>>>(
      sc1, hi1s, lo1s, hi1t, lo1t, hn1, idx1, 4096, 4096);
  select_rescore<2048, 2><<<dim3(256, 4), 256, 0, stream>>>(
      sc2, hi2s, lo2s, hi2t, lo2t, hn2, idx2, 1024, 1024);

  finalize<<<dim3(6144, 4), 256, 0, stream>>>(src1, tar1, src2, tar2, idx1, idx2, out);
}

// Round 11
// 536.105 us; speedup vs baseline: 1.1342x; 1.0425x over previous
//
#include <hip/hip_runtime.h>
#include <cstdint>

using u8 = unsigned char;
using u64 = unsigned long long;

typedef _Float16 f16x8 __attribute__((ext_vector_type(8)));
typedef float f32x4 __attribute__((ext_vector_type(4)));
typedef unsigned short u16x8 __attribute__((ext_vector_type(8)));

__device__ __forceinline__ void gload16(const void* g, void* l) {
  __builtin_amdgcn_global_load_lds((const __attribute__((address_space(1))) void*)g,
                                   (__attribute__((address_space(3))) void*)l, 16, 0, 0);
}

#define VMCNT(N) asm volatile("s_waitcnt vmcnt(" #N ")" ::: "memory")

// ---- fp32 [C][N] slice -> f16 hi/lo planes [N][C] (+ optional partial sum-sq)
__device__ __forceinline__ void split_body(const float* __restrict__ in,
                                           _Float16* __restrict__ hi,
                                           _Float16* __restrict__ lo,
                                           float* __restrict__ hnp,
                                           int C, int N, int NC,
                                           int cblk, int nblk, int b, bool with_hn) {
  const int n = nblk * 256 + (int)threadIdx.x;
  const int c0 = cblk * 32;
  const float* inB = in + (size_t)b * C * N;
  f16x8 hv[4], lv[4];
  float ss = 0.f;
#pragma unroll
  for (int g = 0; g < 4; ++g)
#pragma unroll
    for (int e = 0; e < 8; ++e) {
      float x = inB[(size_t)(c0 + g * 8 + e) * N + n];
      _Float16 h = (_Float16)x;
      float r = (x - (float)h) * 4096.f;
      hv[g][e] = h;
      lv[g][e] = (_Float16)r;
      ss = fmaf(x, x, ss);
    }
  _Float16* oh = hi + ((size_t)b * N + n) * C + c0;
  _Float16* ol = lo + ((size_t)b * N + n) * C + c0;
#pragma unroll
  for (int g = 0; g < 4; ++g) {
    *(f16x8*)(oh + g * 8) = hv[g];
    *(f16x8*)(ol + g * 8) = lv[g];
  }
  if (with_hn) hnp[((size_t)b * NC + cblk) * N + n] = ss;
}

// one launch for all 4 tensors: flat grid 2048*2 (L1) + 1024*2 (L2) = 6144
__global__ __launch_bounds__(256) void prep_all(
    const float* __restrict__ s1, const float* __restrict__ t1,
    const float* __restrict__ s2, const float* __restrict__ t2,
    _Float16* __restrict__ h1s, _Float16* __restrict__ l1s,
    _Float16* __restrict__ h1t, _Float16* __restrict__ l1t,
    _Float16* __restrict__ h2s, _Float16* __restrict__ l2s,
    _Float16* __restrict__ h2t, _Float16* __restrict__ l2t,
    float* __restrict__ hnp1, float* __restrict__ hnp2) {
  const int f = (int)blockIdx.x;
  if (f < 4096) {  // L1: C=1024, N=4096; 32 c-blocks x 16 n-blocks x 4 b
    const bool isT = f >= 2048;
    const int local = f & 2047;
    const int cblk = local & 31;
    const int r = local >> 5;
    const int nblk = r & 15, b = r >> 4;
    split_body(isT ? t1 : s1, isT ? h1t : h1s, isT ? l1t : l1s, hnp1,
               1024, 4096, 32, cblk, nblk, b, isT);
  } else {         // L2: C=2048, N=1024; 64 c-blocks x 4 n-blocks x 4 b
    const int l0 = f - 4096;
    const bool isT = l0 >= 1024;
    const int local = l0 & 1023;
    const int cblk = local & 63;
    const int r = local >> 6;
    const int nblk = r & 3, b = r >> 2;
    split_body(isT ? t2 : s2, isT ? h2t : h2s, isT ? l2t : l2s, hnp2,
               2048, 1024, 64, cblk, nblk, b, isT);
  }
}

// ---- hn[b][n] = 0.5 * sum over chunks, both levels in one launch ------------
__global__ __launch_bounds__(256) void hn_all(const float* __restrict__ hnp1,
                                              const float* __restrict__ hnp2,
                                              float* __restrict__ hn1,
                                              float* __restrict__ hn2) {
  const int x = (int)blockIdx.x, b = (int)blockIdx.y;
  if (x < 16) {
    const int n = x * 256 + (int)threadIdx.x;
    float a = 0.f;
    for (int cc = 0; cc < 32; ++cc) a += hnp1[((size_t)b * 32 + cc) * 4096 + n];
    hn1[(size_t)b * 4096 + n] = 0.5f * a;
  } else {
    const int n = (x - 16) * 256 + (int)threadIdx.x;
    float a = 0.f;
    for (int cc = 0; cc < 64; ++cc) a += hnp2[((size_t)b * 64 + cc) * 1024 + n];
    hn2[(size_t)b * 1024 + n] = 0.5f * a;
  }
}

// ---- f16-hi filter GEMM, validated phase schedule; L1+L2 in ONE launch ------
#define MFMA_BLOCK(GI)                                                         \
  __builtin_amdgcn_s_barrier();                                                \
  asm volatile("s_waitcnt lgkmcnt(0)" ::: "memory");                           \
  __builtin_amdgcn_sched_barrier(0);                                           \
  __builtin_amdgcn_s_setprio(1);                                               \
  _Pragma("unroll") for (int i2 = 0; i2 < 4; ++i2)                             \
      _Pragma("unroll") for (int j = 0; j < NJ; ++j) acc[(GI)*4 + i2][j] =     \
      __builtin_amdgcn_mfma_f32_16x16x32_f16(av[i2], bv[j],                    \
                                             acc[(GI)*4 + i2][j], 0, 0, 0);    \
  __builtin_amdgcn_s_setprio(0);                                               \
  asm volatile("" ::: "memory");                                               \
  __builtin_amdgcn_s_barrier();

// body: 256x256 tile, 512 threads (2x4 waves), MI=8, NJ=4, G=2
__device__ __forceinline__ void filter_body(
    const u8* __restrict__ Ahi, const u8* __restrict__ Bhi,
    const float* __restrict__ hn, unsigned short* __restrict__ sc,
    int M, int N, int NT, int mbase, int nbase, int b, u8* smem) {
  constexpr int MI = 8, NJ = 4;
  constexpr int BM = 256;
  constexpr int CHUNK_A = BM * 64;   // 16 KB
  constexpr int CHUNK = 2 * CHUNK_A; // 32 KB
  constexpr int NTH = 512;

  const int tid = threadIdx.x;
  const int lane = tid & 63;
  const int wid = tid >> 6;
  const int wrow = wid >> 2;   // /4
  const int wcol = wid & 3;    // %4
  const int lr = lane & 15, kh = lane >> 4;
  const size_t rstride = (size_t)NT * 128;

  const int r0 = (tid >> 6) * 16 + ((tid & 63) >> 2);
  const int sA = ((lane & 3) ^ (r0 >> 1)) & 3;
  const u8* aP0 = Ahi + ((size_t)b * M + mbase + r0) * rstride + sA * 16;
  const u8* aP1 = aP0 + (size_t)(NTH / 4) * rstride;
  const u8* bP0 = Bhi + ((size_t)b * N + nbase + r0) * rstride + sA * 16;
  const u8* bP1 = bP0 + (size_t)(NTH / 4) * rstride;

  auto STAGE = [&](int X, int h) {
    const size_t ko = (size_t)X * 128 + h * 64;
    u8* cb = smem + ((X & 1) * 2 + h) * CHUNK;
    gload16(aP0 + ko, cb + tid * 16);
    gload16(aP1 + ko, cb + NTH * 16 + tid * 16);
    gload16(bP0 + ko, cb + CHUNK_A + tid * 16);
    gload16(bP1 + ko, cb + CHUNK_A + NTH * 16 + tid * 16);
  };

  int a_off[MI], b_off[NJ];
#pragma unroll
  for (int i = 0; i < MI; ++i) {
    const int row = wrow * (MI * 16) + i * 16 + lr;
    a_off[i] = row * 64 + (((kh ^ (row >> 1)) & 3) << 4);
  }
#pragma unroll
  for (int j = 0; j < NJ; ++j) {
    const int row = wcol * (NJ * 16) + j * 16 + lr;
    b_off[j] = CHUNK_A + row * 64 + (((kh ^ (row >> 1)) & 3) << 4);
  }

  f32x4 acc[MI][NJ];
#pragma unroll
  for (int i = 0; i < MI; ++i)
#pragma unroll
    for (int j = 0; j < NJ; ++j) acc[i][j] = f32x4{0.f, 0.f, 0.f, 0.f};

  STAGE(0, 0);
  STAGE(0, 1);
  STAGE(1, 0);
  VMCNT(8);
  __builtin_amdgcn_s_barrier();

  for (int X = 0; X < NT; ++X) {
    const u8* cb0 = smem + ((X & 1) * 2) * CHUNK;
    const u8* cb1 = cb0 + CHUNK;
    f16x8 av[4], bv[NJ];

#pragma unroll
    for (int j = 0; j < NJ; ++j) bv[j] = *(const f16x8*)(cb0 + b_off[j]);
#pragma unroll
    for (int i2 = 0; i2 < 4; ++i2) av[i2] = *(const f16x8*)(cb0 + a_off[i2]);
    if (X + 1 < NT) STAGE(X + 1, 1);
    if (X + 1 < NT) { VMCNT(8); } else { VMCNT(0); }
    MFMA_BLOCK(0)

#pragma unroll
    for (int i2 = 0; i2 < 4; ++i2) av[i2] = *(const f16x8*)(cb0 + a_off[4 + i2]);
    MFMA_BLOCK(1)

#pragma unroll
    for (int j = 0; j < NJ; ++j) bv[j] = *(const f16x8*)(cb1 + b_off[j]);
#pragma unroll
    for (int i2 = 0; i2 < 4; ++i2) av[i2] = *(const f16x8*)(cb1 + a_off[i2]);
    if (X + 2 < NT) STAGE(X + 2, 0);
    if (X + 1 < NT) {
      if (X + 2 < NT) { VMCNT(8); } else { VMCNT(4); }
    }
    MFMA_BLOCK(0)

#pragma unroll
    for (int i2 = 0; i2 < 4; ++i2) av[i2] = *(const f16x8*)(cb1 + a_off[4 + i2]);
    MFMA_BLOCK(1)
  }

  // epilogue: quantized score store. C/D: col=lane&15, row=(lane>>4)*4+r
  const float* hnB = hn + (size_t)b * N;
  float hnv[NJ];
  int ncol[NJ];
#pragma unroll
  for (int j = 0; j < NJ; ++j) {
    ncol[j] = nbase + wcol * (NJ * 16) + j * 16 + lr;
    hnv[j] = hnB[ncol[j]];
  }
  unsigned short* scB = sc + (size_t)b * M * N;
#pragma unroll
  for (int i = 0; i < MI; ++i)
#pragma unroll
    for (int r = 0; r < 4; ++r) {
      const int m = mbase + wrow * (MI * 16) + i * 16 + kh * 4 + r;
      unsigned short* srow = scB + (size_t)m * N;
#pragma unroll
      for (int j = 0; j < NJ; ++j) {
        float score = hnv[j] - acc[i][j][r];
        int qi = (int)(score * 64.0f);
        qi = qi < 0 ? 0 : (qi > 65535 ? 65535 : qi);
        srow[ncol[j]] = (unsigned short)qi;
      }
    }
}

// merged launch: blocks [0,64) = L2 (M=N=1024, NT=32, 4x4 grid, long poles
// first), blocks [64, 1088) = L1 (M=N=4096, NT=16, 16x16 grid).
__global__ __launch_bounds__(512, 2) void nn_filter_all(
    const u8* __restrict__ A1, const u8* __restrict__ B1,
    const float* __restrict__ hn1, unsigned short* __restrict__ sc1,
    const u8* __restrict__ A2, const u8* __restrict__ B2,
    const float* __restrict__ hn2, unsigned short* __restrict__ sc2) {
  __shared__ u8 smem[4 * 32768];  // 128 KB
  const int bid = (int)blockIdx.x;
  if (bid < 64) {
    // L2 segment: XCD swizzle within 64 (cpx=8), n-group-of-4 inner
    const int sbid = (bid & 7) * 8 + (bid >> 3);
    const int b = sbid >> 4;
    const int rr = sbid & 15;
    const int n1 = rr & 3;
    const int mb = rr >> 2;       // mBlocks=4, n2=0
    filter_body(A2, B2, hn2, sc2, 1024, 1024, 32, mb * 256, n1 * 256, b, smem);
  } else {
    const int l = bid - 64;       // 1024 blocks, cpx=128
    const int sbid = (l & 7) * 128 + (l >> 3);
    const int perB = 256;         // 16 x 16
    const int b = sbid / perB;
    const int rr = sbid - b * perB;
    const int n1 = rr & 3;
    const int t2 = rr >> 2;
    const int mb = t2 & 15;
    const int n2 = t2 >> 4;
    filter_body(A1, B1, hn1, sc1, 4096, 4096, 16, mb * 256, (n2 * 4 + n1) * 256, b, smem);
  }
}

// ---- select + exact rescore: one wave per source row ------------------------
template <int K, int CH>
__device__ __forceinline__ void select_body(
    const unsigned short* __restrict__ sc,
    const _Float16* __restrict__ hiA, const _Float16* __restrict__ loA,
    const _Float16* __restrict__ hiB, const _Float16* __restrict__ loB,
    const float* __restrict__ hn, unsigned* __restrict__ idx,
    int M, int N, int rowblk, int b) {
  const int w = threadIdx.x >> 6, lane = threadIdx.x & 63;
  const int row = rowblk * 4 + w;
  const unsigned short* q = sc + ((size_t)b * M + row) * N;

  unsigned cm[CH];
#pragma unroll
  for (int ch = 0; ch < CH; ++ch) {
    u16x8 v = *(const u16x8*)(q + ch * 512 + lane * 8);
    unsigned m0 = v[0] < v[1] ? v[0] : v[1];
    unsigned m1 = v[2] < v[3] ? v[2] : v[3];
    unsigned m2 = v[4] < v[5] ? v[4] : v[5];
    unsigned m3 = v[6] < v[7] ? v[6] : v[7];
    m0 = m0 < m1 ? m0 : m1;
    m2 = m2 < m3 ? m2 : m3;
    unsigned m = m0 < m2 ? m0 : m2;
#pragma unroll
    for (int off = 32; off >= 1; off >>= 1) {
      unsigned o = (unsigned)__shfl_xor((int)m, off);
      m = o < m ? o : m;
    }
    cm[ch] = m;
  }
  unsigned mn = 0xFFFFu;
#pragma unroll
  for (int ch = 0; ch < CH; ++ch) mn = cm[ch] < mn ? cm[ch] : mn;
  const unsigned thr = mn + 64;

  constexpr int PER = K / 64;
  const float inv = 2.44140625e-4f;
  float sv[PER];
  const _Float16* hA = hiA + ((size_t)b * M + row) * K;
  const _Float16* lA = loA + ((size_t)b * M + row) * K;
#pragma unroll
  for (int i = 0; i < PER; ++i)
    sv[i] = fmaf((float)lA[i * 64 + lane], inv, (float)hA[i * 64 + lane]);

  float bestv = 3.4e38f;
  int bestn = 0x7FFFFFFF;
  const float* hnB = hn + (size_t)b * N;
#pragma unroll
  for (int ch = 0; ch < CH; ++ch) {
    if (cm[ch] > thr) continue;
    u16x8 v = *(const u16x8*)(q + ch * 512 + lane * 8);
#pragma unroll
    for (int e = 0; e < 8; ++e) {
      u64 mask = __ballot((unsigned)v[e] <= thr);
      while (mask) {
        int bit = __ffsll((long long)mask) - 1;
        mask &= mask - 1;
        int n = ch * 512 + bit * 8 + e;
        const _Float16* hB = hiB + ((size_t)b * N + n) * K;
        const _Float16* lB = loB + ((size_t)b * N + n) * K;
        float part = 0.f;
#pragma unroll
        for (int i = 0; i < PER; ++i)
          part = fmaf(sv[i], fmaf((float)lB[i * 64 + lane], inv, (float)hB[i * 64 + lane]), part);
#pragma unroll
        for (int off = 32; off >= 1; off >>= 1) part += __shfl_xor(part, off);
        float scf = hnB[n] - part;
        if (scf < bestv || (scf == bestv && n < bestn)) { bestv = scf; bestn = n; }
      }
    }
  }
  if (lane == 0) idx[(size_t)b * M + row] = (unsigned)bestn;
}

__global__ __launch_bounds__(256) void select_all(
    const unsigned short* __restrict__ sc1,
    const _Float16* __restrict__ h1s, const _Float16* __restrict__ l1s,
    const _Float16* __restrict__ h1t, const _Float16* __restrict__ l1t,
    const float* __restrict__ hn1, unsigned* __restrict__ idx1,
    const unsigned short* __restrict__ sc2,
    const _Float16* __restrict__ h2s, const _Float16* __restrict__ l2s,
    const _Float16* __restrict__ h2t, const _Float16* __restrict__ l2t,
    const float* __restrict__ hn2, unsigned* __restrict__ idx2) {
  const int x = (int)blockIdx.x, b = (int)blockIdx.y;
  if (x < 1024)
    select_body<1024, 8>(sc1, h1s, l1s, h1t, l1t, hn1, idx1, 4096, 4096, x, b);
  else
    select_body<2048, 2>(sc2, h2s, l2s, h2t, l2t, hn2, idx2, 1024, 1024, x - 1024, b);
}

// ---- finalize: c1 = [src1|gather] and upsampled c2, one launch --------------
__global__ __launch_bounds__(256) void finalize(
    const float* __restrict__ src1, const float* __restrict__ tar1,
    const float* __restrict__ src2, const float* __restrict__ tar2,
    const unsigned* __restrict__ idx1, const unsigned* __restrict__ idx2,
    float* __restrict__ out) {
  const int b = blockIdx.y;
  int c = (int)blockIdx.x;
  if (c < 2048) {
    float* orow = out + ((size_t)b * 6144 + c) * 4096;
    if (c < 1024) {
      const float4* s4 = (const float4*)(src1 + ((size_t)b * 1024 + c) * 4096);
      float4* o4 = (float4*)orow;
#pragma unroll
      for (int i = 0; i < 4; ++i) o4[threadIdx.x + i * 256] = s4[threadIdx.x + i * 256];
    } else {
      const float* trow = tar1 + ((size_t)b * 1024 + (c - 1024)) * 4096;
      const unsigned* ib = idx1 + (size_t)b * 4096;
      for (int p = threadIdx.x; p < 4096; p += 256) orow[p] = trow[ib[p]];
    }
    return;
  }
  c -= 2048;  // upsample channel 0..4095
  __shared__ float row[1024];
  if (c < 2048) {
    const float* in = src2 + ((size_t)b * 2048 + c) * 1024;
    for (int p = threadIdx.x; p < 1024; p += 256) row[p] = in[p];
  } else {
    const float* trow = tar2 + ((size_t)b * 2048 + (c - 2048)) * 1024;
    const unsigned* ib = idx2 + (size_t)b * 1024;
    for (int p = threadIdx.x; p < 1024; p += 256) row[p] = trow[ib[p]];
  }
  __syncthreads();
  float* orow = out + ((size_t)b * 6144 + 2048 + c) * 4096;
  for (int q = threadIdx.x; q < 4096; q += 256) {
    int y = q >> 6, x = q & 63;
    int ky = y >> 1, kx = x >> 1;
    int y0, y1, x0, x1;
    float wy0, wy1, wx0, wx1;
    if (y & 1) { y0 = ky; y1 = (ky + 1 < 32) ? ky + 1 : 31; wy0 = 0.75f; wy1 = 0.25f; }
    else       { y0 = (ky > 0) ? ky - 1 : 0; y1 = ky;       wy0 = 0.25f; wy1 = 0.75f; }
    if (x & 1) { x0 = kx; x1 = (kx + 1 < 32) ? kx + 1 : 31; wx0 = 0.75f; wx1 = 0.25f; }
    else       { x0 = (kx > 0) ? kx - 1 : 0; x1 = kx;       wx0 = 0.25f; wx1 = 0.75f; }
    float v = wy0 * (wx0 * row[y0 * 32 + x0] + wx1 * row[y0 * 32 + x1]) +
              wy1 * (wx0 * row[y1 * 32 + x0] + wx1 * row[y1 * 32 + x1]);
    orow[q] = v;
  }
}

// ---------------- launch -----------------------------------------------------
extern "C" void kernel_launch(void* const* d_in, const int* in_sizes, int n_in,
                              void* d_out, int out_size, void* d_ws, size_t ws_size,
                              hipStream_t stream) {
  const float* src1 = (const float*)d_in[0];  // [4,1024,64,64]
  const float* tar1 = (const float*)d_in[1];
  const float* src2 = (const float*)d_in[2];  // [4,2048,32,32]
  const float* tar2 = (const float*)d_in[3];
  float* out = (float*)d_out;                 // [4,6144,64,64] = 384 MiB

  // scratch in d_out (consumed before the final output writes):
  u8* scratch = (u8*)d_out;
  _Float16* hi1s = (_Float16*)scratch;                       // 32 MiB [4,4096,1024]
  _Float16* lo1s = (_Float16*)(scratch + (32ull << 20));     // 32 MiB
  _Float16* hi1t = (_Float16*)(scratch + (64ull << 20));     // 32 MiB
  _Float16* lo1t = (_Float16*)(scratch + (96ull << 20));     // 32 MiB
  _Float16* hi2s = (_Float16*)(scratch + (128ull << 20));    // 16 MiB [4,1024,2048]
  _Float16* lo2s = (_Float16*)(scratch + (144ull << 20));    // 16 MiB
  _Float16* hi2t = (_Float16*)(scratch + (160ull << 20));    // 16 MiB
  _Float16* lo2t = (_Float16*)(scratch + (176ull << 20));    // 16 MiB
  unsigned short* sc1 = (unsigned short*)(scratch + (192ull << 20));  // 128 MiB
  unsigned short* sc2 = (unsigned short*)(scratch + (320ull << 20));  // 8 MiB
  float* hnp1 = (float*)(scratch + (328ull << 20));          // 2 MiB [4,32,4096]
  float* hnp2 = (float*)(scratch + (331ull << 20));          // 1 MiB [4,64,1024]

  float* hn1 = (float*)d_ws;              // 4*4096 f32
  float* hn2 = hn1 + 4 * 4096;            // 4*1024 f32
  unsigned* idx1 = (unsigned*)(hn2 + 4 * 1024);  // 4*4096 u32
  unsigned* idx2 = idx1 + 4 * 4096;              // 4*1024 u32

  prep_all<<<6144, 256, 0, stream>>>(src1, tar1, src2, tar2,
                                     hi1s, lo1s, hi1t, lo1t,
                                     hi2s, lo2s, hi2t, lo2t, hnp1, hnp2);
  hn_all<<<dim3(20, 4), 256, 0, stream>>>(hnp1, hnp2, hn1, hn2);

  // merged filter: 64 L2 blocks (long poles, first) + 1024 L1 blocks
  nn_filter_all<<<1088, 512, 0, stream>>>(
      (const u8*)hi1s, (const u8*)hi1t, hn1, sc1,
      (const u8*)hi2s, (const u8*)hi2t, hn2, sc2);

  // merged select: 1024 L1 row-blocks + 256 L2 row-blocks
  select_all<<<dim3(1280, 4), 256, 0, stream>>>(
      sc1, hi1s, lo1s, hi1t, lo1t, hn1, idx1,
      sc2, hi2s, lo2s, hi2t, lo2t, hn2, idx2);

  finalize<<<dim3(6144, 4), 256, 0, stream>>>(src1, tar1, src2, tar2, idx1, idx2, out);
}